// Round 4
// baseline (867.856 us; speedup 1.0000x reference)
//
#include <hip/hip_runtime.h>
#include <math.h>
#include <cstdint>

// Problem constants (from reference)
#define Bb 4
#define Ss 2048
#define Hh 1024
#define Ee 8
#define Kk 512
#define Ff 4096

typedef short bf16x8 __attribute__((ext_vector_type(8)));       // 8 bf16 in 4 VGPRs
typedef unsigned short u16x8 __attribute__((ext_vector_type(8)));
typedef float f32x4 __attribute__((ext_vector_type(4)));

// fp32 -> bf16 round-to-nearest-even (bit form)
__device__ __forceinline__ unsigned short f2bf(float f) {
    unsigned int u = __float_as_uint(f);
    u = (u + 0x7FFFu + ((u >> 16) & 1u)) >> 16;
    return (unsigned short)u;
}

// async 16B global->LDS copy (global_load_lds_dwordx4). LDS dest is
// wave-uniform base + lane*16 (m104/m108).
__device__ __forceinline__ void async_copy16(const void* gsrc, void* ldst) {
    auto* g = reinterpret_cast<__attribute__((address_space(1))) void*>(
        reinterpret_cast<uintptr_t>(gsrc));
    auto* l = reinterpret_cast<__attribute__((address_space(3))) void*>(
        (unsigned int)reinterpret_cast<uintptr_t>(ldst));
    __builtin_amdgcn_global_load_lds(g, l, 16, 0, 0);
}

// exact tanh-gelu via fast exp (no libcall)
__device__ __forceinline__ float gelu(float v) {
    float uu = 0.7978845608028654f * (v + 0.044715f * v * v * v);
    float t = __expf(-2.0f * fabsf(uu));
    float th = (1.0f - t) / (1.0f + t);
    th = copysignf(th, uu);
    return 0.5f * v * (1.0f + th);
}

// ---------------------------------------------------------------------------
// 0) x fp32 -> bf16 cast
// ---------------------------------------------------------------------------
__global__ __launch_bounds__(256) void cast_kernel(
    const float4* __restrict__ s, ushort4* __restrict__ d)
{
    int i = blockIdx.x * 256 + threadIdx.x;
    float4 v = s[i];
    ushort4 o;
    o.x = f2bf(v.x); o.y = f2bf(v.y); o.z = f2bf(v.z); o.w = f2bf(v.w);
    d[i] = o;
}

// ---------------------------------------------------------------------------
// 1) Gating: fp64 accumulation so the top-K boundary ranking matches numpy
// ---------------------------------------------------------------------------
__global__ __launch_bounds__(256) void gating_kernel(
    const float* __restrict__ x, const float* __restrict__ wg,
    float* __restrict__ Sm)
{
    int wave = threadIdx.x >> 6;
    int lane = threadIdx.x & 63;
    int token = blockIdx.x * 4 + wave;
    int b = token >> 11, s = token & (Ss - 1);
    const float* xr = x + (size_t)token * Hh;

    double acc[Ee];
#pragma unroll
    for (int e = 0; e < Ee; ++e) acc[e] = 0.0;

    for (int i = 0; i < Hh / 64; ++i) {
        int h = lane + i * 64;
        double xv = (double)xr[h];
#pragma unroll
        for (int e = 0; e < Ee; ++e)
            acc[e] += xv * (double)wg[e * Hh + h];
    }
#pragma unroll
    for (int off = 32; off; off >>= 1) {
#pragma unroll
        for (int e = 0; e < Ee; ++e)
            acc[e] += __shfl_xor(acc[e], off, 64);
    }
    if (lane < Ee) {
        double m = acc[0];
#pragma unroll
        for (int e = 1; e < Ee; ++e) m = acc[e] > m ? acc[e] : m;
        double sum = 0.0;
#pragma unroll
        for (int e = 0; e < Ee; ++e) sum += exp(acc[e] - m);
        double v = exp(acc[lane] - m) / sum;
        Sm[((size_t)(b * Ee + lane)) * Ss + s] = (float)v;
    }
}

// ---------------------------------------------------------------------------
// 2) Top-K per (b,e): bitonic sort of 2048 keys; ties -> lower index first
// ---------------------------------------------------------------------------
__global__ __launch_bounds__(1024) void topk_kernel(
    const float* __restrict__ Sm, int* __restrict__ I, float* __restrict__ G)
{
    __shared__ unsigned long long keys[Ss];
    int be = blockIdx.x;
    const float* row = Sm + (size_t)be * Ss;
    for (int i = threadIdx.x; i < Ss; i += 1024) {
        unsigned int vb = __float_as_uint(row[i]);
        keys[i] = ((unsigned long long)vb << 32) | (unsigned int)(0xFFFFFFFFu - i);
    }
    __syncthreads();
    for (int k = 2; k <= Ss; k <<= 1) {
        for (int j = k >> 1; j > 0; j >>= 1) {
            for (int i = threadIdx.x; i < Ss; i += 1024) {
                int ixj = i ^ j;
                if (ixj > i) {
                    unsigned long long a = keys[i], c = keys[ixj];
                    bool desc = ((i & k) == 0);
                    if (desc ? (a < c) : (a > c)) { keys[i] = c; keys[ixj] = a; }
                }
            }
            __syncthreads();
        }
    }
    if (threadIdx.x < Kk) {
        unsigned long long kk = keys[threadIdx.x];
        I[(size_t)be * Kk + threadIdx.x] = (int)(0xFFFFFFFFu - (unsigned int)(kk & 0xFFFFFFFFu));
        G[(size_t)be * Kk + threadIdx.x] = __uint_as_float((unsigned int)(kk >> 32));
    }
}

// ---------------------------------------------------------------------------
// 3) Transpose + cast fp32 -> bf16, 64x64 tiles.  dst[z][c][r] = src[z][r][c]
//    LDS stored transposed with ODD stride 65: write banks (4a+j+rr) and
//    read banks (a+8b) are at worst 2-way aliased (free, m136).
// ---------------------------------------------------------------------------
__global__ __launch_bounds__(256) void transpose_cast_kernel(
    const float* __restrict__ src, unsigned short* __restrict__ dst, int R, int C)
{
    __shared__ float Lt[64 * 65];   // [c][r] transposed, stride 65
    int z = blockIdx.z;
    const float* s = src + (size_t)z * R * C;
    unsigned short* d = dst + (size_t)z * R * C;
    int c0 = blockIdx.x * 64, r0 = blockIdx.y * 64;
    int t = threadIdx.x;
#pragma unroll
    for (int p = 0; p < 4; ++p) {
        int g = p * 256 + t;
        int rr = g >> 4, cc = (g & 15) * 4;
        float4 v = *(const float4*)(s + (size_t)(r0 + rr) * C + c0 + cc);
        Lt[(cc + 0) * 65 + rr] = v.x;
        Lt[(cc + 1) * 65 + rr] = v.y;
        Lt[(cc + 2) * 65 + rr] = v.z;
        Lt[(cc + 3) * 65 + rr] = v.w;
    }
    __syncthreads();
#pragma unroll
    for (int q = 0; q < 2; ++q) {
        int g = q * 256 + t;
        int cc = g >> 3, rr = (g & 7) * 8;
        u16x8 o;
#pragma unroll
        for (int k = 0; k < 8; ++k) o[k] = f2bf(Lt[cc * 65 + rr + k]);
        *(u16x8*)(d + (size_t)(c0 + cc) * R + r0 + rr) = o;
    }
}

// ---------------------------------------------------------------------------
// GEMM: 128x128 tile, BK=64, 256 threads = 4 waves (2x2), 4x4 MFMA 16x16x32
// per wave.  LDS [128 rows][64 k] bf16, XOR-swizzled 16B granules:
// granule (r, cb) stored at (r, cb ^ (r&7)) -> conflict-free ds_read_b128,
// legal lane-contiguous global_load_lds dest.
// Fragments: A/B [m|n = lane&15][k = quad*8+j]; C/D col=lane&15, row=quad*4+r.
// ---------------------------------------------------------------------------
#define BM 128
#define BN 128
#define BK 64

__global__ __launch_bounds__(256) void gemm1_kernel(
    const unsigned short* __restrict__ xb,   // [B,S,H] bf16
    const unsigned short* __restrict__ w1t,  // [E,F,H] bf16
    const float* __restrict__ b1, const int* __restrict__ I,
    unsigned short* __restrict__ h1,         // [gb,E,K,F] bf16
    int b0)
{
    __shared__ unsigned short As[BM * BK];   // 16 KB
    __shared__ unsigned short Bs[BN * BK];   // 16 KB
    const int e = blockIdx.z;
    const int y = blockIdx.y;
    const int b = b0 + (y >> 2), bl = y >> 2, tm = y & 3;
    const int tn = blockIdx.x;
    const int t = threadIdx.x;
    const int lane = t & 63, w = t >> 6;
    const int wm = (w & 1) * 64, wn = (w >> 1) * 64;
    const int fr = lane & 15, quad = lane >> 4;

    const int sc = (((lane & 7) ^ ((lane >> 3) & 7)) * 8);   // col element offset
    const int rb = w * 32 + (lane >> 3);                      // row base (+ c*8)
    const int ib = (b * Ee + e) * Kk + tm * BM;
    const unsigned short* arow[4];
    const unsigned short* brow[4];
#pragma unroll
    for (int c = 0; c < 4; ++c) {
        int r = rb + c * 8;
        arow[c] = xb + ((size_t)(b * Ss + I[ib + r])) * Hh + sc;
        brow[c] = w1t + ((size_t)e * Ff + tn * BN + r) * Hh + sc;
    }
    char* asDst = (char*)As + w * 4096;
    char* bsDst = (char*)Bs + w * 4096;
    const char* Ab = (const char*)As;
    const char* Bbp = (const char*)Bs;

    f32x4 acc[4][4] = {};
    for (int k0 = 0; k0 < Hh; k0 += BK) {
#pragma unroll
        for (int c = 0; c < 4; ++c) async_copy16(arow[c] + k0, asDst + c * 1024);
#pragma unroll
        for (int c = 0; c < 4; ++c) async_copy16(brow[c] + k0, bsDst + c * 1024);
        __syncthreads();
#pragma unroll
        for (int ks = 0; ks < 2; ++ks) {
            const int sw = ((ks * 4 + quad) ^ (fr & 7)) << 4;
            bf16x8 a[4], bf[4];
#pragma unroll
            for (int i = 0; i < 4; ++i)
                a[i] = *(const bf16x8*)(Ab + ((wm + i * 16 + fr) << 7) + sw);
#pragma unroll
            for (int j = 0; j < 4; ++j)
                bf[j] = *(const bf16x8*)(Bbp + ((wn + j * 16 + fr) << 7) + sw);
#pragma unroll
            for (int i = 0; i < 4; ++i)
#pragma unroll
                for (int j = 0; j < 4; ++j)
                    acc[i][j] = __builtin_amdgcn_mfma_f32_16x16x32_bf16(a[i], bf[j], acc[i][j], 0, 0, 0);
        }
        __syncthreads();
    }

    float bias[4];
#pragma unroll
    for (int j = 0; j < 4; ++j)
        bias[j] = b1[e * Ff + tn * BN + wn + j * 16 + fr];
#pragma unroll
    for (int i = 0; i < 4; ++i) {
#pragma unroll
        for (int r = 0; r < 4; ++r) {
            int mm = tm * BM + wm + i * 16 + quad * 4 + r;
            unsigned short* orow = h1 + (((size_t)bl * Ee + e) * Kk + mm) * Ff + tn * BN + wn + fr;
#pragma unroll
            for (int j = 0; j < 4; ++j)
                orow[j * 16] = f2bf(gelu(acc[i][j][r] + bias[j]));
        }
    }
}

#define KS 2
#define FH (Ff / KS)   // 2048

__global__ __launch_bounds__(256) void gemm2_kernel(
    const unsigned short* __restrict__ h1,   // [gb,E,K,F] bf16
    const unsigned short* __restrict__ w2t,  // [E,H,F] bf16
    const float* __restrict__ b2, const int* __restrict__ I, const float* __restrict__ G,
    float* __restrict__ out, int b0)
{
    __shared__ unsigned short As[BM * BK];
    __shared__ unsigned short Bs[BN * BK];
    const int e = blockIdx.z >> 1, kf = blockIdx.z & 1;
    const int y = blockIdx.y;
    const int b = b0 + (y >> 2), bl = y >> 2, tm = y & 3;
    const int tn = blockIdx.x;
    const int t = threadIdx.x;
    const int lane = t & 63, w = t >> 6;
    const int wm = (w & 1) * 64, wn = (w >> 1) * 64;
    const int fr = lane & 15, quad = lane >> 4;

    const int sc = (((lane & 7) ^ ((lane >> 3) & 7)) * 8);
    const int rb = w * 32 + (lane >> 3);
    const unsigned short* arow[4];
    const unsigned short* brow[4];
#pragma unroll
    for (int c = 0; c < 4; ++c) {
        int r = rb + c * 8;
        arow[c] = h1 + (((size_t)bl * Ee + e) * Kk + tm * BM + r) * Ff + kf * FH + sc;
        brow[c] = w2t + ((size_t)e * Hh + tn * BN + r) * Ff + kf * FH + sc;
    }
    char* asDst = (char*)As + w * 4096;
    char* bsDst = (char*)Bs + w * 4096;
    const char* Ab = (const char*)As;
    const char* Bbp = (const char*)Bs;

    f32x4 acc[4][4] = {};
    for (int k0 = 0; k0 < FH; k0 += BK) {
#pragma unroll
        for (int c = 0; c < 4; ++c) async_copy16(arow[c] + k0, asDst + c * 1024);
#pragma unroll
        for (int c = 0; c < 4; ++c) async_copy16(brow[c] + k0, bsDst + c * 1024);
        __syncthreads();
#pragma unroll
        for (int ks = 0; ks < 2; ++ks) {
            const int sw = ((ks * 4 + quad) ^ (fr & 7)) << 4;
            bf16x8 a[4], bf[4];
#pragma unroll
            for (int i = 0; i < 4; ++i)
                a[i] = *(const bf16x8*)(Ab + ((wm + i * 16 + fr) << 7) + sw);
#pragma unroll
            for (int j = 0; j < 4; ++j)
                bf[j] = *(const bf16x8*)(Bbp + ((wn + j * 16 + fr) << 7) + sw);
#pragma unroll
            for (int i = 0; i < 4; ++i)
#pragma unroll
                for (int j = 0; j < 4; ++j)
                    acc[i][j] = __builtin_amdgcn_mfma_f32_16x16x32_bf16(a[i], bf[j], acc[i][j], 0, 0, 0);
        }
        __syncthreads();
    }

    float bias[4];
#pragma unroll
    for (int j = 0; j < 4; ++j)
        bias[j] = (kf == 0) ? b2[e * Hh + tn * BN + wn + j * 16 + fr] : 0.0f;
#pragma unroll
    for (int i = 0; i < 4; ++i) {
#pragma unroll
        for (int r = 0; r < 4; ++r) {
            int mm = tm * BM + wm + i * 16 + quad * 4 + r;
            int slot = (b * Ee + e) * Kk + mm;
            float gate = G[slot];
            int tok = I[slot];
            float* orow = out + ((size_t)(b * Ss + tok)) * Hh + tn * BN + wn + fr;
#pragma unroll
            for (int j = 0; j < 4; ++j)
                atomicAdd(&orow[j * 16], (acc[i][j][r] + bias[j]) * gate);
        }
    }
}

// ---------------------------------------------------------------------------
extern "C" void kernel_launch(void* const* d_in, const int* in_sizes, int n_in,
                              void* d_out, int out_size, void* d_ws, size_t ws_size,
                              hipStream_t stream) {
    const float* x  = (const float*)d_in[0];   // [B,S,H]
    const float* Wg = (const float*)d_in[1];   // [E,H]
    const float* W1 = (const float*)d_in[2];   // [E,H,F]
    const float* b1 = (const float*)d_in[3];   // [E,F]
    const float* W2 = (const float*)d_in[4];   // [E,F,H]
    const float* b2 = (const float*)d_in[5];   // [E,H]
    float* out = (float*)d_out;                // [B,S,H]

    size_t off = 0;
    char* base = (char*)d_ws;
    auto alloc = [&](size_t bytes) -> void* {
        void* p = base + off;
        off += (bytes + 255) & ~(size_t)255;
        return p;
    };
    float* Sm  = (float*)alloc((size_t)Bb * Ee * Ss * 4);
    int*   I   = (int*)alloc((size_t)Bb * Ee * Kk * 4);
    float* G   = (float*)alloc((size_t)Bb * Ee * Kk * 4);
    unsigned short* W1T = (unsigned short*)alloc((size_t)Ee * Ff * Hh * 2); // [E,F,H]
    unsigned short* W2T = (unsigned short*)alloc((size_t)Ee * Hh * Ff * 2); // [E,H,F]
    unsigned short* xb  = (unsigned short*)alloc((size_t)Bb * Ss * Hh * 2); // [B,S,H]
    size_t fixed = off;
    size_t h1_per_b = (size_t)Ee * Kk * Ff * 2;   // 32 MiB
    int gb = 4;
    while (gb > 1 && fixed + (size_t)gb * h1_per_b > ws_size) gb >>= 1;
    unsigned short* h1 = (unsigned short*)alloc((size_t)gb * h1_per_b);
    if (off > ws_size) return;

    hipMemsetAsync(d_out, 0, (size_t)out_size * sizeof(float), stream);

    cast_kernel<<<(Bb * Ss * Hh) / 1024, 256, 0, stream>>>((const float4*)x, (ushort4*)xb);
    gating_kernel<<<(Bb * Ss) / 4, 256, 0, stream>>>(x, Wg, Sm);
    topk_kernel<<<Bb * Ee, 1024, 0, stream>>>(Sm, I, G);
    transpose_cast_kernel<<<dim3(Ff / 64, Hh / 64, Ee), 256, 0, stream>>>(W1, W1T, Hh, Ff);
    transpose_cast_kernel<<<dim3(Hh / 64, Ff / 64, Ee), 256, 0, stream>>>(W2, W2T, Ff, Hh);

    for (int g = 0; g < Bb / gb; ++g) {
        gemm1_kernel<<<dim3(Ff / BN, 4 * gb, Ee), 256, 0, stream>>>(xb, W1T, b1, I, h1, g * gb);
        gemm2_kernel<<<dim3(Hh / BN, 4 * gb, Ee * KS), 256, 0, stream>>>(h1, W2T, b2, I, G, out, g * gb);
    }
}